// Round 1
// baseline (1138.703 us; speedup 1.0000x reference)
//
#include <hip/hip_runtime.h>

#define NN 100000
#define NE 1600000

// Y[n][j] = dot(X[n], W[:,j])  (+ bias[j] + agg[n][j]/max(deg[n],1) if FUSE)
template<int IN_F, int OUT_F, bool FUSE>
__global__ __launch_bounds__(256) void proj_kernel(
    const float* __restrict__ X, const float* __restrict__ W,
    const float* __restrict__ bias, const float* __restrict__ agg,
    const float* __restrict__ deg, float* __restrict__ Y)
{
    constexpr int NPB = 256 / OUT_F;           // nodes per block
    __shared__ float Wl[IN_F * OUT_F];
    __shared__ float Xl[NPB][IN_F];
    const int tid = threadIdx.x;
    for (int i = tid; i < IN_F * OUT_F; i += 256) Wl[i] = W[i];
    const int nbase = blockIdx.x * NPB;
    for (int i = tid; i < NPB * IN_F; i += 256) {
        int ln = i / IN_F, k = i % IN_F;
        int n = nbase + ln;
        Xl[ln][k] = (n < NN) ? X[(size_t)n * IN_F + k] : 0.f;
    }
    __syncthreads();
    const int j  = tid % OUT_F;
    const int ln = tid / OUT_F;
    const int n  = nbase + ln;
    if (n >= NN) return;
    float acc = 0.f;
#pragma unroll
    for (int k = 0; k < IN_F; ++k) acc += Xl[ln][k] * Wl[k * OUT_F + j];
    if (FUSE) {
        float d = deg[n];
        d = d > 1.f ? d : 1.f;
        acc += bias[j] + agg[(size_t)n * OUT_F + j] / d;
    }
    Y[(size_t)n * OUT_F + j] = acc;
}

// A[dst[e]][:] += P[src[e]][:]  (thread = (edge, 4-feature chunk))
template<int F, bool COUNT_DEG>
__global__ __launch_bounds__(256) void scatter_kernel(
    const float* __restrict__ P, const int* __restrict__ src,
    const int* __restrict__ dst, float* __restrict__ A,
    float* __restrict__ deg)
{
    constexpr int Q  = F / 4;                  // float4 chunks per edge
    constexpr int SH = (Q == 8) ? 3 : 2;
    const long long total  = (long long)NE * Q;
    const long long stride = (long long)gridDim.x * blockDim.x;
    for (long long idx = (long long)blockIdx.x * blockDim.x + threadIdx.x;
         idx < total; idx += stride) {
        const int e = (int)(idx >> SH);
        const int q = (int)(idx & (Q - 1));
        const int s = src[e];
        const int d = dst[e];
        const float4 v = *reinterpret_cast<const float4*>(P + (size_t)s * F + q * 4);
        float* a = A + (size_t)d * F + q * 4;
        atomicAdd(a + 0, v.x);
        atomicAdd(a + 1, v.y);
        atomicAdd(a + 2, v.z);
        atomicAdd(a + 3, v.w);
        if (COUNT_DEG && q == 0) atomicAdd(deg + d, 1.f);
    }
}

extern "C" void kernel_launch(void* const* d_in, const int* in_sizes, int n_in,
                              void* d_out, int out_size, void* d_ws, size_t ws_size,
                              hipStream_t stream)
{
    const float* x   = (const float*)d_in[0];
    const int*   src = (const int*)d_in[1];
    const int*   dst = (const int*)d_in[2];
    const float* Ws1 = (const float*)d_in[3];
    const float* Wn1 = (const float*)d_in[4];
    const float* b1  = (const float*)d_in[5];
    const float* Ws2 = (const float*)d_in[6];
    const float* Wn2 = (const float*)d_in[7];
    const float* b2  = (const float*)d_in[8];
    float* out = (float*)d_out;

    char* ws = (char*)d_ws;
    float* deg = (float*)(ws);                                   // NN floats
    float* B1  = (float*)(ws + (size_t)512 * 1024);              // NN*32 (P1, then P2)
    float* B2  = (float*)(ws + (size_t)(512 + 13 * 1024) * 1024);// NN*32 (A1, then A2)
    float* H1  = (float*)(ws + (size_t)(512 + 26 * 1024) * 1024);// NN*32

    hipMemsetAsync(deg, 0, NN * sizeof(float), stream);
    hipMemsetAsync(B2,  0, (size_t)NN * 32 * sizeof(float), stream);

    // ---- layer 1 ----
    proj_kernel<64, 32, false><<<(NN + 7) / 8, 256, 0, stream>>>(
        x, Wn1, nullptr, nullptr, nullptr, B1);                  // P1 = x @ Wn1
    scatter_kernel<32, true><<<2048, 256, 0, stream>>>(
        B1, src, dst, B2, deg);                                  // A1 += P1[src], deg count
    proj_kernel<64, 32, true><<<(NN + 7) / 8, 256, 0, stream>>>(
        x, Ws1, b1, B2, deg, H1);                                // H1 = x@Ws1 + b1 + A1/deg

    // ---- layer 2 ----
    hipMemsetAsync(B2, 0, (size_t)NN * 16 * sizeof(float), stream);
    proj_kernel<32, 16, false><<<(NN + 15) / 16, 256, 0, stream>>>(
        H1, Wn2, nullptr, nullptr, nullptr, B1);                 // P2 = H1 @ Wn2
    scatter_kernel<16, false><<<2048, 256, 0, stream>>>(
        B1, src, dst, B2, nullptr);                              // A2 += P2[src]
    proj_kernel<32, 16, true><<<(NN + 15) / 16, 256, 0, stream>>>(
        H1, Ws2, b2, B2, deg, out);                              // out = H1@Ws2 + b2 + A2/deg
}

// Round 2
// 332.326 us; speedup vs baseline: 3.4265x; 3.4265x over previous
//
#include <hip/hip_runtime.h>

#define NN 100000
#define NE 1600000
#define NBLK ((NN + 255) / 256)   // 391 scan blocks

// ---- CSR construction -------------------------------------------------------

__global__ __launch_bounds__(256) void hist_kernel(const int* __restrict__ dst,
                                                   int* __restrict__ cnt) {
    int e = blockIdx.x * 256 + threadIdx.x;
    if (e < NE) atomicAdd(&cnt[dst[e]], 1);
}

// per-block inclusive scan -> exclusive offsets within block + block sums
__global__ __launch_bounds__(256) void scan1_kernel(const int* __restrict__ cnt,
                                                    int* __restrict__ off,
                                                    int* __restrict__ bsum) {
    __shared__ int s[256];
    int i = blockIdx.x * 256 + threadIdx.x;
    int v = (i < NN) ? cnt[i] : 0;
    s[threadIdx.x] = v;
    __syncthreads();
    for (int d = 1; d < 256; d <<= 1) {
        int t = (threadIdx.x >= d) ? s[threadIdx.x - d] : 0;
        __syncthreads();
        s[threadIdx.x] += t;
        __syncthreads();
    }
    if (i < NN) off[i] = s[threadIdx.x] - v;
    if (threadIdx.x == 255) bsum[blockIdx.x] = s[255];
}

// scan the 391 block sums in one block
__global__ __launch_bounds__(512) void scan2_kernel(const int* __restrict__ bsum,
                                                    int* __restrict__ boff) {
    __shared__ int s[512];
    int tid = threadIdx.x;
    int v = (tid < NBLK) ? bsum[tid] : 0;
    s[tid] = v;
    __syncthreads();
    for (int d = 1; d < 512; d <<= 1) {
        int t = (tid >= d) ? s[tid - d] : 0;
        __syncthreads();
        s[tid] += t;
        __syncthreads();
    }
    boff[tid] = s[tid] - v;
}

__global__ __launch_bounds__(256) void scan3_kernel(int* __restrict__ off,
                                                    const int* __restrict__ boff) {
    int i = blockIdx.x * 256 + threadIdx.x;
    if (i < NN) off[i] += boff[i >> 8];
    else if (i == NN) off[NN] = NE;
}

// bucket-fill, using off[] itself as the cursor: after this kernel,
// off[n] == end-of-bucket(n) == original off[n+1]; start(n) = (n? off[n-1]:0)
__global__ __launch_bounds__(256) void fill_kernel(const int* __restrict__ src,
                                                   const int* __restrict__ dst,
                                                   int* __restrict__ off,
                                                   int* __restrict__ esrc) {
    int e = blockIdx.x * 256 + threadIdx.x;
    if (e >= NE) return;
    int pos = atomicAdd(&off[dst[e]], 1);
    esrc[pos] = src[e];
}

// ---- gather-aggregate: A[n][:] = sum_{e in bucket(n)} P[esrc[e]][:] ---------

template<int F>
__global__ __launch_bounds__(256) void agg_kernel(const float* __restrict__ P,
                                                  const int* __restrict__ esrc,
                                                  const int* __restrict__ off,
                                                  float* __restrict__ A) {
    constexpr int Q = F / 4;
    int t = blockIdx.x * 256 + threadIdx.x;
    int n = t / Q, q = t % Q;
    if (n >= NN) return;
    int e0 = (n > 0) ? off[n - 1] : 0;   // post-fill semantics
    int e1 = off[n];
    float4 a0 = {0.f, 0.f, 0.f, 0.f}, a1 = {0.f, 0.f, 0.f, 0.f};
    int e = e0;
    for (; e + 1 < e1; e += 2) {
        int s0 = esrc[e], s1 = esrc[e + 1];
        const float4 v0 = *reinterpret_cast<const float4*>(P + (size_t)s0 * F + q * 4);
        const float4 v1 = *reinterpret_cast<const float4*>(P + (size_t)s1 * F + q * 4);
        a0.x += v0.x; a0.y += v0.y; a0.z += v0.z; a0.w += v0.w;
        a1.x += v1.x; a1.y += v1.y; a1.z += v1.z; a1.w += v1.w;
    }
    if (e < e1) {
        int s0 = esrc[e];
        const float4 v0 = *reinterpret_cast<const float4*>(P + (size_t)s0 * F + q * 4);
        a0.x += v0.x; a0.y += v0.y; a0.z += v0.z; a0.w += v0.w;
    }
    float4 r;
    r.x = a0.x + a1.x; r.y = a0.y + a1.y; r.z = a0.z + a1.z; r.w = a0.w + a1.w;
    *reinterpret_cast<float4*>(A + (size_t)n * F + q * 4) = r;
}

// ---- dense projection (+ fused mean/bias epilogue) --------------------------
// Y[n][j] = dot(X[n], W[:,j])  (+ bias[j] + agg[n][j]/max(cnt[n],1) if FUSE)
template<int IN_F, int OUT_F, bool FUSE>
__global__ __launch_bounds__(256) void proj_kernel(
    const float* __restrict__ X, const float* __restrict__ W,
    const float* __restrict__ bias, const float* __restrict__ agg,
    const int* __restrict__ cnt, float* __restrict__ Y)
{
    constexpr int NPB = 256 / OUT_F;           // nodes per block
    __shared__ float Wl[IN_F * OUT_F];
    __shared__ float Xl[NPB][IN_F];
    const int tid = threadIdx.x;
    for (int i = tid; i < IN_F * OUT_F; i += 256) Wl[i] = W[i];
    const int nbase = blockIdx.x * NPB;
    for (int i = tid; i < NPB * IN_F; i += 256) {
        int ln = i / IN_F, k = i % IN_F;
        int n = nbase + ln;
        Xl[ln][k] = (n < NN) ? X[(size_t)n * IN_F + k] : 0.f;
    }
    __syncthreads();
    const int j  = tid % OUT_F;
    const int ln = tid / OUT_F;
    const int n  = nbase + ln;
    if (n >= NN) return;
    float acc = 0.f;
#pragma unroll
    for (int k = 0; k < IN_F; ++k) acc += Xl[ln][k] * Wl[k * OUT_F + j];
    if (FUSE) {
        float d = (float)cnt[n];
        if (d < 1.f) d = 1.f;
        acc += bias[j] + agg[(size_t)n * OUT_F + j] / d;
    }
    Y[(size_t)n * OUT_F + j] = acc;
}

// ---- launch -----------------------------------------------------------------

extern "C" void kernel_launch(void* const* d_in, const int* in_sizes, int n_in,
                              void* d_out, int out_size, void* d_ws, size_t ws_size,
                              hipStream_t stream)
{
    const float* x   = (const float*)d_in[0];
    const int*   src = (const int*)d_in[1];
    const int*   dst = (const int*)d_in[2];
    const float* Ws1 = (const float*)d_in[3];
    const float* Wn1 = (const float*)d_in[4];
    const float* b1  = (const float*)d_in[5];
    const float* Ws2 = (const float*)d_in[6];
    const float* Wn2 = (const float*)d_in[7];
    const float* b2  = (const float*)d_in[8];
    float* out = (float*)d_out;

    char* ws = (char*)d_ws;
    int* cnt   = (int*)(ws);                          // 400 KB  (degree)
    int* off   = (int*)(ws + (512u << 10));           // 400 KB + 4
    int* bsum  = (int*)(ws + (1024u << 10));          // 2 KB
    int* boff  = (int*)(ws + (1024u << 10) + 4096);   // 2 KB
    int* esrc  = (int*)(ws + (2048u << 10));          // 6.4 MB
    float* R1  = (float*)(ws + (9u << 20));           // 12.8 MB: P1, then H1
    float* R2  = (float*)(ws + (22u << 20));          // 12.8 MB: A1, then P2|A2
    float* P2  = R2;                                  // NN*16 = 6.4 MB
    float* A2  = R2 + (size_t)NN * 16;                // NN*16 = 6.4 MB

    // ---- CSR build (shared by both layers) ----
    hipMemsetAsync(cnt, 0, NN * sizeof(int), stream);
    hist_kernel <<<(NE + 255) / 256, 256, 0, stream>>>(dst, cnt);
    scan1_kernel<<<NBLK, 256, 0, stream>>>(cnt, off, bsum);
    scan2_kernel<<<1, 512, 0, stream>>>(bsum, boff);
    scan3_kernel<<<(NN + 1 + 255) / 256, 256, 0, stream>>>(off, boff);
    fill_kernel <<<(NE + 255) / 256, 256, 0, stream>>>(src, dst, off, esrc);

    // ---- layer 1 ----
    proj_kernel<64, 32, false><<<(NN + 7) / 8, 256, 0, stream>>>(
        x, Wn1, nullptr, nullptr, nullptr, R1);            // P1 = x @ Wn1
    agg_kernel<32><<<(NN * 8 + 255) / 256, 256, 0, stream>>>(
        R1, esrc, off, R2);                                // A1 = sum P1[src]
    proj_kernel<64, 32, true><<<(NN + 7) / 8, 256, 0, stream>>>(
        x, Ws1, b1, R2, cnt, R1);                          // H1 = x@Ws1+b1+A1/deg

    // ---- layer 2 ----
    proj_kernel<32, 16, false><<<(NN + 15) / 16, 256, 0, stream>>>(
        R1, Wn2, nullptr, nullptr, nullptr, P2);           // P2 = H1 @ Wn2
    agg_kernel<16><<<(NN * 4 + 255) / 256, 256, 0, stream>>>(
        P2, esrc, off, A2);                                // A2 = sum P2[src]
    proj_kernel<32, 16, true><<<(NN + 15) / 16, 256, 0, stream>>>(
        R1, Ws2, b2, A2, cnt, out);                        // out = H1@Ws2+b2+A2/deg
}